// Round 1
// baseline (413.556 us; speedup 1.0000x reference)
//
#include <hip/hip_runtime.h>

// TemporalAttention: B=16, T=48, N=256, D=64, H=8, hs=8
// Kernel 1: per-(b,t) K/V projections -> workspace (fp32, 100.7 MB)
// Kernel 2: per-(b,n) fused temporal attention + proj1(tanh) + proj2 -> out

#define B_ 16
#define T_ 48
#define N_ 256
#define D_ 64
#define H_ 8
#define HS_ 8

// ---------------------------------------------------------------------------
// Kernel A: k = key @ key_w[b,t] + key_b[b,t]; v likewise (blockIdx.y selects)
// grid (B*T, 2), 256 threads. LDS: W 16KB + 64-row input tile 16.6KB.
// Thread (tr,tc) computes a 4x4 (n,e) tile; W read as float4.
// ---------------------------------------------------------------------------
__global__ __launch_bounds__(256) void proj_kv_kernel(
    const float* __restrict__ key, const float* __restrict__ key_w, const float* __restrict__ key_b,
    const float* __restrict__ value, const float* __restrict__ value_w, const float* __restrict__ value_b,
    float* __restrict__ k_out, float* __restrict__ v_out)
{
    const int bt = blockIdx.x;
    const int which = blockIdx.y;
    const float* __restrict__ in = (which ? value : key) + (size_t)bt * N_ * D_;
    const float* __restrict__ w  = (which ? value_w : key_w) + (size_t)bt * D_ * D_;
    const float* __restrict__ bb = (which ? value_b : key_b) + (size_t)bt * D_;
    float* __restrict__ out = (which ? v_out : k_out) + (size_t)bt * N_ * D_;

    __shared__ float Wl[D_][D_];       // [d][e]
    __shared__ float Xl[64][D_ + 1];   // 64 input rows per pass, +1 pad
    __shared__ float Bl[D_];

    const int tid = threadIdx.x;
    #pragma unroll
    for (int i = tid; i < D_ * D_; i += 256) Wl[i >> 6][i & 63] = w[i];
    if (tid < D_) Bl[tid] = bb[tid];

    const int tc = tid & 15;   // col group (4 cols)
    const int tr = tid >> 4;   // row group (4 rows)

    for (int n0 = 0; n0 < N_; n0 += 64) {
        __syncthreads();   // also covers Wl-write -> Wl-read on first pass
        #pragma unroll
        for (int i = tid; i < 64 * D_; i += 256) Xl[i >> 6][i & 63] = in[(size_t)n0 * D_ + i];
        __syncthreads();

        float acc[4][4];
        #pragma unroll
        for (int j = 0; j < 4; ++j) {
            #pragma unroll
            for (int i = 0; i < 4; ++i) acc[j][i] = Bl[tc * 4 + i];
        }

        #pragma unroll 8
        for (int d = 0; d < D_; ++d) {
            const float4 bv = *(const float4*)&Wl[d][tc * 4];
            #pragma unroll
            for (int j = 0; j < 4; ++j) {
                const float a = Xl[tr * 4 + j][d];
                acc[j][0] += a * bv.x;
                acc[j][1] += a * bv.y;
                acc[j][2] += a * bv.z;
                acc[j][3] += a * bv.w;
            }
        }

        #pragma unroll
        for (int j = 0; j < 4; ++j) {
            const float4 st = make_float4(acc[j][0], acc[j][1], acc[j][2], acc[j][3]);
            *(float4*)&out[(size_t)(n0 + tr * 4 + j) * D_ + tc * 4] = st;
        }
    }
}

// ---------------------------------------------------------------------------
// Kernel B: per (b,n): temporal attention over T=48 (all 8 heads) + proj1/proj2.
// grid (B*N = 4096), 384 threads (6 waves).
// Attention: thread = (q = tid%48, h = tid/48); online softmax (no max needed:
// tanh(s/denom) in (0, 0.77)). Q LDS buffer reused for x_att; K reused for x1.
// ---------------------------------------------------------------------------
__global__ __launch_bounds__(384) void attn_proj_kernel(
    const float* __restrict__ query, const float* __restrict__ k_in, const float* __restrict__ v_in,
    const float* __restrict__ p1w, const float* __restrict__ p1b,
    const float* __restrict__ p2w, const float* __restrict__ p2b,
    const float* __restrict__ rate, float* __restrict__ out)
{
    const int b = blockIdx.x >> 8;
    const int n = blockIdx.x & 255;

    __shared__ float Q[T_][68];    // query rows; later x_att
    __shared__ float K[T_][68];    // projected keys; later x1 = tanh(proj1)
    __shared__ float V[T_][68];
    __shared__ float W1[D_][68];   // W1[d][c] = p1w[c*64+d] (transposed)
    __shared__ float W2[D_][68];
    __shared__ float B1[D_], B2[D_];

    const int tid = threadIdx.x;
    #pragma unroll
    for (int i = tid; i < T_ * D_; i += 384) {
        const int t = i >> 6, d = i & 63;
        const size_t g = ((size_t)(b * T_ + t) * N_ + n) * D_ + d;
        Q[t][d] = query[g];
        K[t][d] = k_in[g];
        V[t][d] = v_in[g];
    }
    for (int i = tid; i < D_ * D_; i += 384) {
        const int c = i >> 6, d = i & 63;
        W1[d][c] = p1w[i];
        W2[d][c] = p2w[i];
    }
    if (tid < D_) { B1[tid] = p1b[tid]; B2[tid] = p2b[tid]; }
    const float rsig = 1.0f / (1.0f + __expf(-rate[0]));
    __syncthreads();

    // ---- attention ----
    const int q = tid % 48;
    const int h = tid / 48;
    float qf[8];
    #pragma unroll
    for (int d = 0; d < 8; ++d) qf[d] = Q[q][h * 8 + d];
    const float rd = rsig * (float)(T_ - q);   // sigmoid(rate) * time_decay(q)

    float acc[8] = {0.f, 0.f, 0.f, 0.f, 0.f, 0.f, 0.f, 0.f};
    float ssum = 0.f;
    #pragma unroll 4
    for (int tk = 0; tk < T_; ++tk) {
        float sc = 0.f;
        #pragma unroll
        for (int d = 0; d < 8; ++d) sc += qf[d] * K[tk][h * 8 + d];
        sc *= 0.35355339059327373f;                       // 1/sqrt(hs)
        const float s  = 1.0f / (1.0f + __expf(-sc));     // sigmoid(scores)
        const float s2 = 1.0f / (1.0f + __expf(-s * rd)); // sigmoid(s*sig(rate)*dec)
        const float arg = s / (1.0f + s2);
        const float th = 1.0f - 2.0f / (__expf(2.0f * arg) + 1.0f);  // tanh(arg)
        const float e = __expf(th);                        // softmax numerator
        ssum += e;
        #pragma unroll
        for (int d = 0; d < 8; ++d) acc[d] += e * V[tk][h * 8 + d];
    }
    const float inv = 1.0f / ssum;

    __syncthreads();   // all threads done reading Q (qf is in regs)
    #pragma unroll
    for (int d = 0; d < 8; ++d) Q[q][h * 8 + d] = acc[d] * inv;   // x_att
    __syncthreads();

    // ---- proj1: x1 = tanh(x_att @ W1^T + b1) -> K buffer ----
    const int cg = tid & 7;    // 8 cols per thread
    const int qr = tid >> 3;   // row 0..47
    {
        float a2[8];
        #pragma unroll
        for (int i = 0; i < 8; ++i) a2[i] = B1[cg * 8 + i];
        #pragma unroll 8
        for (int d = 0; d < D_; ++d) {
            const float xv = Q[qr][d];
            const float4 w0 = *(const float4*)&W1[d][cg * 8];
            const float4 w1 = *(const float4*)&W1[d][cg * 8 + 4];
            a2[0] += xv * w0.x; a2[1] += xv * w0.y; a2[2] += xv * w0.z; a2[3] += xv * w0.w;
            a2[4] += xv * w1.x; a2[5] += xv * w1.y; a2[6] += xv * w1.z; a2[7] += xv * w1.w;
        }
        #pragma unroll
        for (int i = 0; i < 8; ++i) {
            const float x = a2[i];
            K[qr][cg * 8 + i] = 1.0f - 2.0f / (__expf(2.0f * x) + 1.0f);  // tanh
        }
    }
    __syncthreads();

    // ---- proj2: out = x1 @ W2^T + b2 ----
    {
        float a3[8];
        #pragma unroll
        for (int i = 0; i < 8; ++i) a3[i] = B2[cg * 8 + i];
        #pragma unroll 8
        for (int d = 0; d < D_; ++d) {
            const float xv = K[qr][d];
            const float4 w0 = *(const float4*)&W2[d][cg * 8];
            const float4 w1 = *(const float4*)&W2[d][cg * 8 + 4];
            a3[0] += xv * w0.x; a3[1] += xv * w0.y; a3[2] += xv * w0.z; a3[3] += xv * w0.w;
            a3[4] += xv * w1.x; a3[5] += xv * w1.y; a3[6] += xv * w1.z; a3[7] += xv * w1.w;
        }
        const size_t og = ((size_t)(b * T_ + qr) * N_ + n) * D_ + cg * 8;
        *(float4*)&out[og]     = make_float4(a3[0], a3[1], a3[2], a3[3]);
        *(float4*)&out[og + 4] = make_float4(a3[4], a3[5], a3[6], a3[7]);
    }
}

extern "C" void kernel_launch(void* const* d_in, const int* in_sizes, int n_in,
                              void* d_out, int out_size, void* d_ws, size_t ws_size,
                              hipStream_t stream) {
    const float* query   = (const float*)d_in[0];
    const float* key     = (const float*)d_in[1];
    const float* value   = (const float*)d_in[2];
    const float* key_w   = (const float*)d_in[3];
    const float* key_b   = (const float*)d_in[4];
    const float* value_w = (const float*)d_in[5];
    const float* value_b = (const float*)d_in[6];
    const float* p1w     = (const float*)d_in[7];
    const float* p1b     = (const float*)d_in[8];
    const float* p2w     = (const float*)d_in[9];
    const float* p2b     = (const float*)d_in[10];
    const float* rate    = (const float*)d_in[11];
    float* out = (float*)d_out;

    // workspace: projected k and v, fp32, 2 * 16*48*256*64 * 4B = 100,663,296 B
    float* kws = (float*)d_ws;
    float* vws = kws + (size_t)B_ * T_ * N_ * D_;

    dim3 gridA(B_ * T_, 2);
    proj_kv_kernel<<<gridA, 256, 0, stream>>>(key, key_w, key_b, value, value_w, value_b, kws, vws);
    attn_proj_kernel<<<B_ * N_, 384, 0, stream>>>(query, kws, vws, p1w, p1b, p2w, p2b, rate, out);
}

// Round 2
// 259.291 us; speedup vs baseline: 1.5950x; 1.5950x over previous
//
#include <hip/hip_runtime.h>

// TemporalAttention: B=16, T=48, N=256, D=64, H=8, hs=8
// Kernel A: per-(b,t) K/V projections -> workspace (fp32, 100.7 MB)
// Kernel B: per-(b,n) temporal attention (writes x_att over the k workspace)
// Kernel C: fused proj1(tanh)+proj2 over all B*T*N rows

#define B_ 16
#define T_ 48
#define N_ 256
#define D_ 64
#define H_ 8
#define HS_ 8

__device__ __forceinline__ float rcpf(float x) { return __builtin_amdgcn_rcpf(x); }

// ---------------------------------------------------------------------------
// Kernel A: k = key @ key_w[b,t] + key_b[b,t]; v likewise (blockIdx.y selects)
// ---------------------------------------------------------------------------
__global__ __launch_bounds__(256) void proj_kv_kernel(
    const float* __restrict__ key, const float* __restrict__ key_w, const float* __restrict__ key_b,
    const float* __restrict__ value, const float* __restrict__ value_w, const float* __restrict__ value_b,
    float* __restrict__ k_out, float* __restrict__ v_out)
{
    const int bt = blockIdx.x;
    const int which = blockIdx.y;
    const float* __restrict__ in = (which ? value : key) + (size_t)bt * N_ * D_;
    const float* __restrict__ w  = (which ? value_w : key_w) + (size_t)bt * D_ * D_;
    const float* __restrict__ bb = (which ? value_b : key_b) + (size_t)bt * D_;
    float* __restrict__ out = (which ? v_out : k_out) + (size_t)bt * N_ * D_;

    __shared__ float Wl[D_][D_];       // [d][e]
    __shared__ float Xl[64][D_ + 1];
    __shared__ float Bl[D_];

    const int tid = threadIdx.x;
    #pragma unroll
    for (int i = tid; i < D_ * D_; i += 256) Wl[i >> 6][i & 63] = w[i];
    if (tid < D_) Bl[tid] = bb[tid];

    const int tc = tid & 15;
    const int tr = tid >> 4;

    for (int n0 = 0; n0 < N_; n0 += 64) {
        __syncthreads();
        #pragma unroll
        for (int i = tid; i < 64 * D_; i += 256) Xl[i >> 6][i & 63] = in[(size_t)n0 * D_ + i];
        __syncthreads();

        float acc[4][4];
        #pragma unroll
        for (int j = 0; j < 4; ++j) {
            #pragma unroll
            for (int i = 0; i < 4; ++i) acc[j][i] = Bl[tc * 4 + i];
        }

        #pragma unroll 8
        for (int d = 0; d < D_; ++d) {
            const float4 bv = *(const float4*)&Wl[d][tc * 4];
            #pragma unroll
            for (int j = 0; j < 4; ++j) {
                const float a = Xl[tr * 4 + j][d];
                acc[j][0] += a * bv.x;
                acc[j][1] += a * bv.y;
                acc[j][2] += a * bv.z;
                acc[j][3] += a * bv.w;
            }
        }

        #pragma unroll
        for (int j = 0; j < 4; ++j) {
            const float4 st = make_float4(acc[j][0], acc[j][1], acc[j][2], acc[j][3]);
            *(float4*)&out[(size_t)(n0 + tr * 4 + j) * D_ + tc * 4] = st;
        }
    }
}

// ---------------------------------------------------------------------------
// Kernel B: per (b,n): temporal attention over T=48, all 8 heads.
// grid (B*N = 4096), 384 threads (6 waves). LDS 39.4 KB -> 4 blocks/CU.
// Writes x_att back over the k workspace region (same element set it read).
// ---------------------------------------------------------------------------
__global__ __launch_bounds__(384) void attn_kernel(
    const float* __restrict__ query, float* __restrict__ k_xatt, const float* __restrict__ v_in,
    const float* __restrict__ rate)
{
    const int b = blockIdx.x >> 8;
    const int n = blockIdx.x & 255;

    __shared__ float Q[T_][68];    // query rows; later x_att
    __shared__ float K[T_][68];
    __shared__ float V[T_][68];

    const int tid = threadIdx.x;
    #pragma unroll
    for (int i = tid; i < T_ * D_; i += 384) {
        const int t = i >> 6, d = i & 63;
        const size_t g = ((size_t)(b * T_ + t) * N_ + n) * D_ + d;
        Q[t][d] = query[g];
        K[t][d] = k_xatt[g];
        V[t][d] = v_in[g];
    }
    const float rsig = rcpf(1.0f + __expf(-rate[0]));
    __syncthreads();

    const int q = tid % 48;
    const int h = tid / 48;
    float qf[8];
    #pragma unroll
    for (int d = 0; d < 8; ++d) qf[d] = Q[q][h * 8 + d];
    const float rd = rsig * (float)(T_ - q);

    float acc[8] = {0.f, 0.f, 0.f, 0.f, 0.f, 0.f, 0.f, 0.f};
    float ssum = 0.f;
    #pragma unroll 4
    for (int tk = 0; tk < T_; ++tk) {
        float sc = 0.f;
        #pragma unroll
        for (int d = 0; d < 8; ++d) sc += qf[d] * K[tk][h * 8 + d];
        sc *= 0.35355339059327373f;                        // 1/sqrt(hs)
        const float s   = rcpf(1.0f + __expf(-sc));        // sigmoid(scores)
        const float s2  = rcpf(1.0f + __expf(-s * rd));    // sigmoid(s*sig(rate)*dec)
        const float arg = s * rcpf(1.0f + s2);
        const float th  = 1.0f - 2.0f * rcpf(__expf(2.0f * arg) + 1.0f);  // tanh
        const float e   = __expf(th);
        ssum += e;
        #pragma unroll
        for (int d = 0; d < 8; ++d) acc[d] += e * V[tk][h * 8 + d];
    }
    const float inv = rcpf(ssum);

    __syncthreads();
    #pragma unroll
    for (int d = 0; d < 8; ++d) Q[q][h * 8 + d] = acc[d] * inv;   // x_att
    __syncthreads();

    // coalesced store of x_att over the k workspace slots this block consumed
    #pragma unroll
    for (int i = tid; i < T_ * D_; i += 384) {
        const int t = i >> 6, d = i & 63;
        k_xatt[((size_t)(b * T_ + t) * N_ + n) * D_ + d] = Q[t][d];
    }
}

// ---------------------------------------------------------------------------
// Kernel C: out = tanh(x_att @ W1^T + b1) @ W2^T + b2, rows = B*T*N = 196608.
// 64 rows/block, 512 threads; thread = (row r = tid>>3, colgroup cg = tid&7).
// LDS 52.7 KB -> 3 blocks/CU. X buffer reused for x1.
// ---------------------------------------------------------------------------
__global__ __launch_bounds__(512) void out_proj_kernel(
    const float* __restrict__ xatt,
    const float* __restrict__ p1w, const float* __restrict__ p1b,
    const float* __restrict__ p2w, const float* __restrict__ p2b,
    float* __restrict__ out)
{
    __shared__ float W1t[D_][68];   // W1t[d][c] = p1w[c*64+d]
    __shared__ float W2t[D_][68];
    __shared__ float X[64][68];
    __shared__ float B1[D_], B2[D_];

    const int tid = threadIdx.x;
    const size_t m0 = (size_t)blockIdx.x * 64;

    #pragma unroll
    for (int i = tid; i < D_ * D_; i += 512) {
        const int c = i >> 6, d = i & 63;
        W1t[d][c] = p1w[i];
        W2t[d][c] = p2w[i];
    }
    #pragma unroll
    for (int i = tid; i < 64 * D_; i += 512) X[i >> 6][i & 63] = xatt[m0 * D_ + i];
    if (tid < D_) { B1[tid] = p1b[tid]; B2[tid] = p2b[tid]; }
    __syncthreads();

    const int cg = tid & 7;
    const int r  = tid >> 3;

    // proj1 + tanh
    float x1[8];
    {
        float a[8];
        #pragma unroll
        for (int i = 0; i < 8; ++i) a[i] = B1[cg * 8 + i];
        #pragma unroll 8
        for (int d = 0; d < D_; ++d) {
            const float xv = X[r][d];
            const float4 w0 = *(const float4*)&W1t[d][cg * 8];
            const float4 w1 = *(const float4*)&W1t[d][cg * 8 + 4];
            a[0] += xv * w0.x; a[1] += xv * w0.y; a[2] += xv * w0.z; a[3] += xv * w0.w;
            a[4] += xv * w1.x; a[5] += xv * w1.y; a[6] += xv * w1.z; a[7] += xv * w1.w;
        }
        #pragma unroll
        for (int i = 0; i < 8; ++i)
            x1[i] = 1.0f - 2.0f * rcpf(__expf(2.0f * a[i]) + 1.0f);   // tanh
    }
    __syncthreads();
    #pragma unroll
    for (int i = 0; i < 8; ++i) X[r][cg * 8 + i] = x1[i];
    __syncthreads();

    // proj2
    {
        float a[8];
        #pragma unroll
        for (int i = 0; i < 8; ++i) a[i] = B2[cg * 8 + i];
        #pragma unroll 8
        for (int d = 0; d < D_; ++d) {
            const float xv = X[r][d];
            const float4 w0 = *(const float4*)&W2t[d][cg * 8];
            const float4 w1 = *(const float4*)&W2t[d][cg * 8 + 4];
            a[0] += xv * w0.x; a[1] += xv * w0.y; a[2] += xv * w0.z; a[3] += xv * w0.w;
            a[4] += xv * w1.x; a[5] += xv * w1.y; a[6] += xv * w1.z; a[7] += xv * w1.w;
        }
        const size_t og = (m0 + r) * D_ + cg * 8;
        *(float4*)&out[og]     = make_float4(a[0], a[1], a[2], a[3]);
        *(float4*)&out[og + 4] = make_float4(a[4], a[5], a[6], a[7]);
    }
}

extern "C" void kernel_launch(void* const* d_in, const int* in_sizes, int n_in,
                              void* d_out, int out_size, void* d_ws, size_t ws_size,
                              hipStream_t stream) {
    const float* query   = (const float*)d_in[0];
    const float* key     = (const float*)d_in[1];
    const float* value   = (const float*)d_in[2];
    const float* key_w   = (const float*)d_in[3];
    const float* key_b   = (const float*)d_in[4];
    const float* value_w = (const float*)d_in[5];
    const float* value_b = (const float*)d_in[6];
    const float* p1w     = (const float*)d_in[7];
    const float* p1b     = (const float*)d_in[8];
    const float* p2w     = (const float*)d_in[9];
    const float* p2b     = (const float*)d_in[10];
    const float* rate    = (const float*)d_in[11];
    float* out = (float*)d_out;

    // workspace: projected k (later overwritten by x_att) and v
    float* kws = (float*)d_ws;
    float* vws = kws + (size_t)B_ * T_ * N_ * D_;

    dim3 gridA(B_ * T_, 2);
    proj_kv_kernel<<<gridA, 256, 0, stream>>>(key, key_w, key_b, value, value_w, value_b, kws, vws);
    attn_kernel<<<B_ * N_, 384, 0, stream>>>(query, kws, vws, rate);
    out_proj_kernel<<<(B_ * T_ * N_) / 64, 512, 0, stream>>>(kws, p1w, p1b, p2w, p2b, out);
}

// Round 3
// 222.790 us; speedup vs baseline: 1.8563x; 1.1638x over previous
//
#include <hip/hip_runtime.h>

// TemporalAttention: B=16, T=48, N=256, D=64, H=8, hs=8
// Kernel A: per-(b,t) K/V projections -> workspace (fp32, 100.7 MB)
// Kernel B: per-(b,n) temporal attention (writes x_att over the k workspace)
// Kernel C: fused proj1(tanh)+proj2 over all B*T*N rows

#define B_ 16
#define T_ 48
#define N_ 256
#define D_ 64
#define H_ 8
#define HS_ 8

__device__ __forceinline__ float rcpf(float x) { return __builtin_amdgcn_rcpf(x); }
__device__ __forceinline__ float ex2(float x) { return __builtin_amdgcn_exp2f(x); }

#define LOG2E 1.4426950408889634f

// ---------------------------------------------------------------------------
// Kernel A: k = key @ key_w[b,t] + key_b[b,t]; v likewise (blockIdx.y selects)
// 256 threads, 128-row tiles; thread = (rg=tid>>3 -> rows rg+32j, cg=tid&7 -> 8 cols)
// ---------------------------------------------------------------------------
__global__ __launch_bounds__(256) void proj_kv_kernel(
    const float* __restrict__ key, const float* __restrict__ key_w, const float* __restrict__ key_b,
    const float* __restrict__ value, const float* __restrict__ value_w, const float* __restrict__ value_b,
    float* __restrict__ k_out, float* __restrict__ v_out)
{
    const int bt = blockIdx.x;
    const int which = blockIdx.y;
    const float* __restrict__ in = (which ? value : key) + (size_t)bt * N_ * D_;
    const float* __restrict__ w  = (which ? value_w : key_w) + (size_t)bt * D_ * D_;
    const float* __restrict__ bb = (which ? value_b : key_b) + (size_t)bt * D_;
    float* __restrict__ out = (which ? v_out : k_out) + (size_t)bt * N_ * D_;

    __shared__ float Wl[D_][D_];     // [d][e], 256B rows (16B-aligned for b128)
    __shared__ float Xl[128][68];    // 272B rows, 16B-aligned
    __shared__ float Bl[D_];

    const int tid = threadIdx.x;
    #pragma unroll
    for (int i = tid; i < D_ * D_; i += 256) Wl[i >> 6][i & 63] = w[i];
    if (tid < D_) Bl[tid] = bb[tid];

    const int cg = tid & 7;    // 8 cols
    const int rg = tid >> 3;   // 0..31 -> rows rg+32j, j=0..3

    for (int n0 = 0; n0 < N_; n0 += 128) {
        __syncthreads();
        #pragma unroll
        for (int i = tid; i < 128 * D_ / 4; i += 256) {
            const int e = i * 4;
            *(float4*)&Xl[e >> 6][e & 63] = *(const float4*)&in[(size_t)n0 * D_ + e];
        }
        __syncthreads();

        float acc[4][8];
        #pragma unroll
        for (int j = 0; j < 4; ++j)
            #pragma unroll
            for (int i = 0; i < 8; ++i) acc[j][i] = Bl[cg * 8 + i];

        #pragma unroll 8
        for (int d = 0; d < D_; ++d) {
            const float4 w0 = *(const float4*)&Wl[d][cg * 8];
            const float4 w1 = *(const float4*)&Wl[d][cg * 8 + 4];
            #pragma unroll
            for (int j = 0; j < 4; ++j) {
                const float a = Xl[rg + 32 * j][d];
                acc[j][0] += a * w0.x; acc[j][1] += a * w0.y;
                acc[j][2] += a * w0.z; acc[j][3] += a * w0.w;
                acc[j][4] += a * w1.x; acc[j][5] += a * w1.y;
                acc[j][6] += a * w1.z; acc[j][7] += a * w1.w;
            }
        }

        #pragma unroll
        for (int j = 0; j < 4; ++j) {
            const size_t row = (size_t)(n0 + rg + 32 * j);
            *(float4*)&out[row * D_ + cg * 8]     = make_float4(acc[j][0], acc[j][1], acc[j][2], acc[j][3]);
            *(float4*)&out[row * D_ + cg * 8 + 4] = make_float4(acc[j][4], acc[j][5], acc[j][6], acc[j][7]);
        }
    }
}

// ---------------------------------------------------------------------------
// Kernel B: per (b,n): temporal attention over T=48, all 8 heads.
// grid (B*N = 4096), 384 threads (6 waves). LDS 39.4 KB -> 4 blocks/CU.
// float4 LDS fragment reads; exp folded to raw v_exp_f32 with pre-scaled consts.
// Writes x_att back over the k workspace region (same element set it read).
// ---------------------------------------------------------------------------
__global__ __launch_bounds__(384) void attn_kernel(
    const float* __restrict__ query, float* __restrict__ k_xatt, const float* __restrict__ v_in,
    const float* __restrict__ rate)
{
    const int b = blockIdx.x >> 8;
    const int n = blockIdx.x & 255;

    __shared__ float Q[T_][68];    // query rows; later x_att
    __shared__ float K[T_][68];
    __shared__ float V[T_][68];

    const int tid = threadIdx.x;
    // float4 staging: T_*D_/4 = 768 vec4 elements
    #pragma unroll
    for (int i = tid; i < T_ * D_ / 4; i += 384) {
        const int e = i * 4;
        const int t = e >> 6, d = e & 63;
        const size_t g = ((size_t)(b * T_ + t) * N_ + n) * D_ + d;
        *(float4*)&Q[t][d] = *(const float4*)&query[g];
        *(float4*)&K[t][d] = *(const float4*)&k_xatt[g];
        *(float4*)&V[t][d] = *(const float4*)&v_in[g];
    }
    const float rsig = rcpf(1.0f + ex2(-rate[0] * LOG2E));
    __syncthreads();

    const int q = tid % 48;
    const int h = tid / 48;

    // q fragment pre-scaled by -log2e/sqrt(8): dot accumulates the exp2 exponent
    const float C1 = 0.35355339059327373f * LOG2E;
    float4 qa = *(const float4*)&Q[q][h * 8];
    float4 qb = *(const float4*)&Q[q][h * 8 + 4];
    qa.x *= -C1; qa.y *= -C1; qa.z *= -C1; qa.w *= -C1;
    qb.x *= -C1; qb.y *= -C1; qb.z *= -C1; qb.w *= -C1;
    const float rdn = -rsig * (float)(T_ - q) * LOG2E;

    float4 acc0 = make_float4(0.f, 0.f, 0.f, 0.f);
    float4 acc1 = make_float4(0.f, 0.f, 0.f, 0.f);
    float ssum = 0.f;
    #pragma unroll 4
    for (int tk = 0; tk < T_; ++tk) {
        const float4 ka = *(const float4*)&K[tk][h * 8];
        const float4 kb = *(const float4*)&K[tk][h * 8 + 4];
        const float dn = qa.x * ka.x + qa.y * ka.y + qa.z * ka.z + qa.w * ka.w
                       + qb.x * kb.x + qb.y * kb.y + qb.z * kb.z + qb.w * kb.w;   // = -log2e*sc
        const float s   = rcpf(1.0f + ex2(dn));              // sigmoid(scores)
        const float s2  = rcpf(1.0f + ex2(s * rdn));         // sigmoid(s*sig(rate)*dec)
        const float arg = s * rcpf(1.0f + s2);
        const float th  = 1.0f - 2.0f * rcpf(ex2(arg * (2.0f * LOG2E)) + 1.0f);  // tanh
        const float e   = ex2(th * LOG2E);                   // exp(th)
        ssum += e;
        const float4 va = *(const float4*)&V[tk][h * 8];
        const float4 vb = *(const float4*)&V[tk][h * 8 + 4];
        acc0.x += e * va.x; acc0.y += e * va.y; acc0.z += e * va.z; acc0.w += e * va.w;
        acc1.x += e * vb.x; acc1.y += e * vb.y; acc1.z += e * vb.z; acc1.w += e * vb.w;
    }
    const float inv = rcpf(ssum);

    __syncthreads();
    acc0.x *= inv; acc0.y *= inv; acc0.z *= inv; acc0.w *= inv;
    acc1.x *= inv; acc1.y *= inv; acc1.z *= inv; acc1.w *= inv;
    *(float4*)&Q[q][h * 8]     = acc0;   // x_att
    *(float4*)&Q[q][h * 8 + 4] = acc1;
    __syncthreads();

    // coalesced float4 store of x_att over the k workspace slots this block consumed
    #pragma unroll
    for (int i = tid; i < T_ * D_ / 4; i += 384) {
        const int e = i * 4;
        const int t = e >> 6, d = e & 63;
        *(float4*)&k_xatt[((size_t)(b * T_ + t) * N_ + n) * D_ + d] = *(const float4*)&Q[t][d];
    }
}

// ---------------------------------------------------------------------------
// Kernel C: out = tanh(x_att @ W1^T + b1) @ W2^T + b2, rows = B*T*N = 196608.
// 128 rows/block, 512 threads; thread = (rp = tid>>3 -> rows rp, rp+64; cg = tid&7).
// LDS ~70 KB -> 2 blocks/CU. X buffer reused for x1.
// ---------------------------------------------------------------------------
__global__ __launch_bounds__(512) void out_proj_kernel(
    const float* __restrict__ xatt,
    const float* __restrict__ p1w, const float* __restrict__ p1b,
    const float* __restrict__ p2w, const float* __restrict__ p2b,
    float* __restrict__ out)
{
    __shared__ float W1t[D_][68];   // W1t[d][c] = p1w[c*64+d]
    __shared__ float W2t[D_][68];
    __shared__ float X[128][68];
    __shared__ float B1[D_], B2[D_];

    const int tid = threadIdx.x;
    const size_t m0 = (size_t)blockIdx.x * 128;

    #pragma unroll
    for (int i = tid; i < D_ * D_; i += 512) {
        const int c = i >> 6, d = i & 63;
        W1t[d][c] = p1w[i];
        W2t[d][c] = p2w[i];
    }
    #pragma unroll
    for (int i = tid; i < 128 * D_ / 4; i += 512) {
        const int e = i * 4;
        *(float4*)&X[e >> 6][e & 63] = *(const float4*)&xatt[m0 * D_ + e];
    }
    if (tid < D_) { B1[tid] = p1b[tid]; B2[tid] = p2b[tid]; }
    __syncthreads();

    const int cg = tid & 7;
    const int rp = tid >> 3;   // 0..63 -> rows rp, rp+64

    // proj1 + tanh
    float x1a[8], x1b[8];
    {
        float a[8], b2r[8];
        #pragma unroll
        for (int i = 0; i < 8; ++i) { a[i] = B1[cg * 8 + i]; b2r[i] = B1[cg * 8 + i]; }
        #pragma unroll 8
        for (int d = 0; d < D_; ++d) {
            const float xv0 = X[rp][d];
            const float xv1 = X[rp + 64][d];
            const float4 w0 = *(const float4*)&W1t[d][cg * 8];
            const float4 w1 = *(const float4*)&W1t[d][cg * 8 + 4];
            a[0] += xv0 * w0.x; a[1] += xv0 * w0.y; a[2] += xv0 * w0.z; a[3] += xv0 * w0.w;
            a[4] += xv0 * w1.x; a[5] += xv0 * w1.y; a[6] += xv0 * w1.z; a[7] += xv0 * w1.w;
            b2r[0] += xv1 * w0.x; b2r[1] += xv1 * w0.y; b2r[2] += xv1 * w0.z; b2r[3] += xv1 * w0.w;
            b2r[4] += xv1 * w1.x; b2r[5] += xv1 * w1.y; b2r[6] += xv1 * w1.z; b2r[7] += xv1 * w1.w;
        }
        #pragma unroll
        for (int i = 0; i < 8; ++i) {
            x1a[i] = 1.0f - 2.0f * rcpf(ex2(a[i]   * (2.0f * LOG2E)) + 1.0f);
            x1b[i] = 1.0f - 2.0f * rcpf(ex2(b2r[i] * (2.0f * LOG2E)) + 1.0f);
        }
    }
    __syncthreads();
    #pragma unroll
    for (int i = 0; i < 8; ++i) {
        X[rp][cg * 8 + i]      = x1a[i];
        X[rp + 64][cg * 8 + i] = x1b[i];
    }
    __syncthreads();

    // proj2
    {
        float a[8], b2r[8];
        #pragma unroll
        for (int i = 0; i < 8; ++i) { a[i] = B2[cg * 8 + i]; b2r[i] = B2[cg * 8 + i]; }
        #pragma unroll 8
        for (int d = 0; d < D_; ++d) {
            const float xv0 = X[rp][d];
            const float xv1 = X[rp + 64][d];
            const float4 w0 = *(const float4*)&W2t[d][cg * 8];
            const float4 w1 = *(const float4*)&W2t[d][cg * 8 + 4];
            a[0] += xv0 * w0.x; a[1] += xv0 * w0.y; a[2] += xv0 * w0.z; a[3] += xv0 * w0.w;
            a[4] += xv0 * w1.x; a[5] += xv0 * w1.y; a[6] += xv0 * w1.z; a[7] += xv0 * w1.w;
            b2r[0] += xv1 * w0.x; b2r[1] += xv1 * w0.y; b2r[2] += xv1 * w0.z; b2r[3] += xv1 * w0.w;
            b2r[4] += xv1 * w1.x; b2r[5] += xv1 * w1.y; b2r[6] += xv1 * w1.z; b2r[7] += xv1 * w1.w;
        }
        const size_t og0 = (m0 + rp) * D_ + cg * 8;
        const size_t og1 = (m0 + rp + 64) * D_ + cg * 8;
        *(float4*)&out[og0]     = make_float4(a[0], a[1], a[2], a[3]);
        *(float4*)&out[og0 + 4] = make_float4(a[4], a[5], a[6], a[7]);
        *(float4*)&out[og1]     = make_float4(b2r[0], b2r[1], b2r[2], b2r[3]);
        *(float4*)&out[og1 + 4] = make_float4(b2r[4], b2r[5], b2r[6], b2r[7]);
    }
}

extern "C" void kernel_launch(void* const* d_in, const int* in_sizes, int n_in,
                              void* d_out, int out_size, void* d_ws, size_t ws_size,
                              hipStream_t stream) {
    const float* query   = (const float*)d_in[0];
    const float* key     = (const float*)d_in[1];
    const float* value   = (const float*)d_in[2];
    const float* key_w   = (const float*)d_in[3];
    const float* key_b   = (const float*)d_in[4];
    const float* value_w = (const float*)d_in[5];
    const float* value_b = (const float*)d_in[6];
    const float* p1w     = (const float*)d_in[7];
    const float* p1b     = (const float*)d_in[8];
    const float* p2w     = (const float*)d_in[9];
    const float* p2b     = (const float*)d_in[10];
    const float* rate    = (const float*)d_in[11];
    float* out = (float*)d_out;

    float* kws = (float*)d_ws;
    float* vws = kws + (size_t)B_ * T_ * N_ * D_;

    dim3 gridA(B_ * T_, 2);
    proj_kv_kernel<<<gridA, 256, 0, stream>>>(key, key_w, key_b, value, value_w, value_b, kws, vws);
    attn_kernel<<<B_ * N_, 384, 0, stream>>>(query, kws, vws, rate);
    out_proj_kernel<<<(B_ * T_ * N_) / 128, 512, 0, stream>>>(kws, p1w, p1b, p2w, p2b, out);
}